// Round 9
// baseline (88.243 us; speedup 1.0000x reference)
//
#include <hip/hip_runtime.h>
#include <hip/hip_bf16.h>
#include <stdint.h>

#define NE 8
#define DK 1024
#define FN 1024
#define NTOK 8192

#define BM 320
#define BN 256
#define BK 64
#define NIT (DK / BK)
#define MT 52            // max m-tiles per expert: ceil(16384/320)

#define HB 32
#define EPB (NTOK * 2 / HB)

// LDS map per buffer: A [320 rows x 128B] @0 (40960B), B-kh0 @40960 (16384B),
// B-kh1 @57344 (16384B); buffer stride 73728B; 2 buffers = 144KB.
#define BUFS 73728
#define BOFF 40960

typedef __attribute__((ext_vector_type(4))) float f32x4;
typedef __attribute__((ext_vector_type(8))) short short8;
typedef __attribute__((ext_vector_type(4))) short short4v;

__device__ __forceinline__ unsigned short f2bf(float f) {
    union { float f; unsigned u; } v; v.f = f;
    unsigned r = v.u;
    unsigned lsb = (r >> 16) & 1u;
    r += 0x7fffu + lsb;
    return (unsigned short)(r >> 16);
}
__device__ __forceinline__ float bf2f(unsigned short u) {
    union { unsigned u; float f; } v; v.u = ((unsigned)u) << 16;
    return v.f;
}

// ---------------- gating + x -> bf16 conversion (one wave per token) ---------
__global__ __launch_bounds__(256) void k_gate(const float* __restrict__ x,
    const float* __restrict__ Wg, const float* __restrict__ bg,
    unsigned short* __restrict__ xb, int* __restrict__ meta_e,
    float* __restrict__ meta_w)
{
    const int lane = threadIdx.x & 63;
    const int t = blockIdx.x * 4 + (threadIdx.x >> 6);

    const f32x4* xr = (const f32x4*)(x + (size_t)t * DK);
    f32x4 xv[4];
#pragma unroll
    for (int c = 0; c < 4; ++c) xv[c] = xr[lane + 64 * c];

    short4v* xbo = (short4v*)(xb + (size_t)t * DK);
#pragma unroll
    for (int c = 0; c < 4; ++c) {
        short4v b;
        b.x = (short)f2bf(xv[c].x); b.y = (short)f2bf(xv[c].y);
        b.z = (short)f2bf(xv[c].z); b.w = (short)f2bf(xv[c].w);
        xbo[lane + 64 * c] = b;
    }

    float acc[NE];
#pragma unroll
    for (int e = 0; e < NE; ++e) {
        const f32x4* wr = (const f32x4*)(Wg + e * DK);
        float a = 0.f;
#pragma unroll
        for (int c = 0; c < 4; ++c) {
            f32x4 wv = wr[lane + 64 * c];
            a += xv[c].x * wv.x + xv[c].y * wv.y + xv[c].z * wv.z + xv[c].w * wv.w;
        }
        acc[e] = a;
    }
#pragma unroll
    for (int e = 0; e < NE; ++e) {
        float a = acc[e];
#pragma unroll
        for (int off = 32; off > 0; off >>= 1) a += __shfl_xor(a, off, 64);
        acc[e] = a;
    }
    if (lane == 0) {
        float v[NE];
#pragma unroll
        for (int e = 0; e < NE; ++e) v[e] = acc[e] + bg[e];
        int b0 = 0; float m0 = v[0];
#pragma unroll
        for (int e = 1; e < NE; ++e) if (v[e] > m0) { m0 = v[e]; b0 = e; }
        int b1 = -1; float m1 = -3.4e38f;
#pragma unroll
        for (int e = 0; e < NE; ++e) if (e != b0 && v[e] > m1) { m1 = v[e]; b1 = e; }
        float r = expf(m1 - m0);
        float s = 1.f + r;
        meta_e[2 * t] = b0; meta_e[2 * t + 1] = b1;
        meta_w[2 * t] = 1.f / s; meta_w[2 * t + 1] = r / s;
    }
}

// ---------------- W -> bf16 ---------------------------------------------------
__global__ __launch_bounds__(256) void k_convw(const float* __restrict__ W,
                                               unsigned short* __restrict__ Wb)
{
    int i = blockIdx.x * 256 + threadIdx.x;
    f32x4 v = ((const f32x4*)W)[i];
    short4v b;
    b.x = (short)f2bf(v.x); b.y = (short)f2bf(v.y);
    b.z = (short)f2bf(v.z); b.w = (short)f2bf(v.w);
    ((short4v*)Wb)[i] = b;
}

// ---------------- per-block histogram (LDS atomics only) ---------------------
__global__ __launch_bounds__(256) void k_hist(const int* __restrict__ meta_e,
                                              int* __restrict__ blockcnt)
{
    __shared__ int lh[NE];
    if (threadIdx.x < NE) lh[threadIdx.x] = 0;
    __syncthreads();
    int base = blockIdx.x * EPB;
#pragma unroll
    for (int k = 0; k < EPB / 256; ++k)
        atomicAdd(&lh[meta_e[base + k * 256 + threadIdx.x]], 1);
    __syncthreads();
    if (threadIdx.x < NE) blockcnt[blockIdx.x * NE + threadIdx.x] = lh[threadIdx.x];
}

// ---------------- scan: expert segs + per-block bases ------------------------
__global__ void k_scan(const int* __restrict__ blockcnt, int* __restrict__ seg,
                       int* __restrict__ base)
{
    __shared__ int pre[HB][NE];
    __shared__ int colsum[NE];
    __shared__ int segstart[NE];
    int tid = threadIdx.x;
    if (tid < NE) {
        int run = 0;
        for (int b = 0; b < HB; ++b) { pre[b][tid] = run; run += blockcnt[b * NE + tid]; }
        colsum[tid] = run;
    }
    __syncthreads();
    if (tid == 0) {
        int s = 0;
        for (int e = 0; e < NE; ++e) { segstart[e] = s; seg[e] = s; s += colsum[e]; }
        seg[NE] = s;
    }
    __syncthreads();
    for (int i = tid; i < HB * NE; i += 64) {
        int b = i / NE, e = i % NE;
        base[i] = segstart[e] + pre[b][e];
    }
}

// ---------------- scatter: ridx[p] = 2t+k (orig slot), rw[p] = weight --------
__global__ __launch_bounds__(256) void k_scatter(const int* __restrict__ meta_e,
    const float* __restrict__ meta_w, const int* __restrict__ base,
    int* __restrict__ ridx, float* __restrict__ rw)
{
    __shared__ int lh[NE];
    __shared__ int bb[NE];
    if (threadIdx.x < NE) {
        lh[threadIdx.x] = 0;
        bb[threadIdx.x] = base[blockIdx.x * NE + threadIdx.x];
    }
    __syncthreads();
    int bs = blockIdx.x * EPB;
#pragma unroll
    for (int k = 0; k < EPB / 256; ++k) {
        int i = bs + k * 256 + threadIdx.x;
        int e = meta_e[i];
        int r = atomicAdd(&lh[e], 1);
        int p = bb[e] + r;
        ridx[p] = i;
        rw[p] = meta_w[i];
    }
}

// ---------------- grouped GEMM, 320x256, 4-phase m201-style pipeline ---------
// 8 waves (2M x 4N), per-wave 160x64, acc[10][4]. 4 phases/tile, 20 MFMA each:
//  P0: vmcnt(2)|bar -> read B0(4)+A0-4 -> STAGE_A(t+1) -> lgkm0 -> MFMA kk0 lo
//  P1:          bar -> read A5-9       -> STAGE_B0(t+1)-> lgkm0 -> MFMA kk0 hi
//  P2: vmcnt(7)|bar -> read B1(4)+A0-4 -> STAGE_B1(t+1)-> lgkm0 -> MFMA kk1 lo
//  P3:          bar -> read A5-9       ->               lgkm0 -> MFMA kk1 hi
// vmcnt proof (in-order retire): issue/tile = [A:5@P0][B0:2@P1][B1:2@P2].
// At P0(t): in flight A(t)5+B0(t)2+B1(t)2=9; vmcnt(2) retires A+B0.
// At P2(t): in flight B1(t)2+A(t+1)5+B0(t+1)2=9; vmcnt(7) retires B1(t).
// Last tile: vmcnt(0). WAR: every wave lgkm(0)s its reads before the next
// barrier, so post-barrier stages never overwrite in-flight reads.
template <int MODE>
__global__ __launch_bounds__(512, 2) void k_gemm(const unsigned short* __restrict__ xb,
    const unsigned short* __restrict__ Wb, const float* __restrict__ be,
    const int* __restrict__ seg, const int* __restrict__ ridx,
    const float* __restrict__ rw, float* __restrict__ out, void* __restrict__ ywv)
{
    __shared__ char Lds[2 * BUFS];   // 144 KB

    const int bid = blockIdx.x;
    const int e = bid & 7;                       // XCD-pinned expert
    const int n0 = ((bid >> 3) & 3) * BN;
    const int mt = bid >> 5;
    const int s0 = seg[e];
    const int L = seg[e + 1] - s0;
    const int m0 = mt * BM;
    if (m0 >= L) return;

    const int tid = threadIdx.x;
    const int lane = tid & 63;
    const int wid = tid >> 6;
    const int wm = wid >> 2, wn = wid & 3;       // 2 x 4 wave grid

    // A staging: instr c covers rows c*64 + tid/8; granule g = (tid&7)^((tid>>3)&7)
    const int ag = ((tid & 7) ^ ((tid >> 3) & 7)) * 8;
    const unsigned short* asrc[5];
#pragma unroll
    for (int c = 0; c < 5; ++c) {
        int r = c * 64 + (tid >> 3);
        int idx = m0 + r; if (idx >= L) idx = L - 1;
        asrc[c] = xb + (size_t)(ridx[s0 + idx] >> 1) * DK + ag;
    }
    // B staging (kh halves): instr c covers rows c*128 + tid/4
    const int bgr = ((tid & 3) ^ ((tid >> 3) & 3)) * 8;
    const unsigned short* bsrc[2];
#pragma unroll
    for (int c = 0; c < 2; ++c) {
        int r = c * 128 + (tid >> 2);
        bsrc[c] = Wb + ((size_t)e * FN + n0 + r) * DK + bgr;
    }

    char* LB = (char*)Lds;

    f32x4 acc[10][4];
#pragma unroll
    for (int i = 0; i < 10; ++i)
#pragma unroll
        for (int j = 0; j < 4; ++j) acc[i][j] = f32x4{0.f, 0.f, 0.f, 0.f};

    const int frow = lane & 15;
    const int fq = lane >> 4;
    int a_off[10][2], b_off[4][2];
#pragma unroll
    for (int mi = 0; mi < 10; ++mi) {
        int r = wm * 160 + mi * 16 + frow;
#pragma unroll
        for (int kk = 0; kk < 2; ++kk)
            a_off[mi][kk] = r * 128 + (((kk * 4 + fq) ^ (r & 7)) * 16);
    }
#pragma unroll
    for (int ni = 0; ni < 4; ++ni) {
        int r = wn * 64 + ni * 16 + frow;
        int sl = fq ^ ((r >> 1) & 3);
#pragma unroll
        for (int kk = 0; kk < 2; ++kk)
            b_off[ni][kk] = BOFF + kk * 16384 + r * 64 + sl * 16;
    }

    auto STAGE_A = [&](int buf, int kt) {
        const int ko = kt * BK;
        char* dst = LB + buf * BUFS + wid * 1024;
#pragma unroll
        for (int c = 0; c < 5; ++c)
            __builtin_amdgcn_global_load_lds(
                (const __attribute__((address_space(1))) void*)(asrc[c] + ko),
                (__attribute__((address_space(3))) void*)(dst + c * 8192), 16, 0, 0);
    };
    auto STAGE_B = [&](int buf, int kt, int kh) {
        const int ko = kt * BK + kh * 32;
        char* dst = LB + buf * BUFS + BOFF + kh * 16384 + wid * 1024;
#pragma unroll
        for (int c = 0; c < 2; ++c)
            __builtin_amdgcn_global_load_lds(
                (const __attribute__((address_space(1))) void*)(bsrc[c] + ko),
                (__attribute__((address_space(3))) void*)(dst + c * 8192), 16, 0, 0);
    };

#define GATE(N) do { asm volatile("s_waitcnt vmcnt(" #N ")" ::: "memory"); \
                     __builtin_amdgcn_s_barrier(); \
                     __builtin_amdgcn_sched_barrier(0); } while (0)
#define BARP  do { __builtin_amdgcn_s_barrier(); \
                   __builtin_amdgcn_sched_barrier(0); } while (0)
#define LGKM0 do { asm volatile("s_waitcnt lgkmcnt(0)" ::: "memory"); \
                   __builtin_amdgcn_sched_barrier(0); } while (0)
#define MFMA5(AF, BF, MLO) do { \
    __builtin_amdgcn_s_setprio(1); \
    _Pragma("unroll") \
    for (int mi = 0; mi < 5; ++mi) { \
        _Pragma("unroll") \
        for (int ni = 0; ni < 4; ++ni) \
            acc[(MLO) + mi][ni] = __builtin_amdgcn_mfma_f32_16x16x32_bf16( \
                AF[mi], BF[ni], acc[(MLO) + mi][ni], 0, 0, 0); \
    } \
    __builtin_amdgcn_s_setprio(0); } while (0)

    // prologue: tile 0 -> buf 0 (A:5, B0:2, B1:2 = 9 outstanding)
    STAGE_A(0, 0); STAGE_B(0, 0, 0); STAGE_B(0, 0, 1);
    __builtin_amdgcn_sched_barrier(0);

    for (int t = 0; t < NIT; ++t) {
        const int b = t & 1;
        const char* Cb = LB + b * BUFS;
        const bool st = (t + 1 < NIT);
        short8 b0f[4], b1f[4], af[5];

        // ---- P0: gate A(t)+B0(t); kk0 x mi 0-4 ----
        GATE(2);
#pragma unroll
        for (int ni = 0; ni < 4; ++ni) b0f[ni] = *(const short8*)(Cb + b_off[ni][0]);
#pragma unroll
        for (int mi = 0; mi < 5; ++mi) af[mi] = *(const short8*)(Cb + a_off[mi][0]);
        if (st) STAGE_A(b ^ 1, t + 1);
        LGKM0;
        MFMA5(af, b0f, 0);

        // ---- P1: kk0 x mi 5-9 ----
        BARP;
#pragma unroll
        for (int mi = 0; mi < 5; ++mi) af[mi] = *(const short8*)(Cb + a_off[5 + mi][0]);
        if (st) STAGE_B(b ^ 1, t + 1, 0);
        LGKM0;
        MFMA5(af, b0f, 5);

        // ---- P2: gate B1(t); kk1 x mi 0-4 ----
        if (st) { GATE(7); } else { GATE(0); }
#pragma unroll
        for (int ni = 0; ni < 4; ++ni) b1f[ni] = *(const short8*)(Cb + b_off[ni][1]);
#pragma unroll
        for (int mi = 0; mi < 5; ++mi) af[mi] = *(const short8*)(Cb + a_off[mi][1]);
        if (st) STAGE_B(b ^ 1, t + 1, 1);
        LGKM0;
        MFMA5(af, b1f, 0);

        // ---- P3: kk1 x mi 5-9 ----
        BARP;
#pragma unroll
        for (int mi = 0; mi < 5; ++mi) af[mi] = *(const short8*)(Cb + a_off[5 + mi][1]);
        LGKM0;
        MFMA5(af, b1f, 5);
    }
#undef GATE
#undef BARP
#undef LGKM0
#undef MFMA5

    // epilogue: D col = lane&15, row = (lane>>4)*4 + j
    float bias_n[4];
#pragma unroll
    for (int ni = 0; ni < 4; ++ni)
        bias_n[ni] = be[e * FN + n0 + wn * 64 + ni * 16 + frow];

    const int fq4 = fq * 4;
#pragma unroll
    for (int mi = 0; mi < 10; ++mi) {
        int rl = m0 + wm * 160 + mi * 16 + fq4;
#pragma unroll
        for (int j = 0; j < 4; ++j) {
            int idx = rl + j;
            if (idx < L) {
                float w = rw[s0 + idx];
                int oi = ridx[s0 + idx];
                if (MODE == 0) {
                    float* orow = out + (size_t)(oi >> 1) * FN + n0 + wn * 64 + frow;
#pragma unroll
                    for (int ni = 0; ni < 4; ++ni)
                        atomicAdd(orow + ni * 16, w * (acc[mi][ni][j] + bias_n[ni]));
                } else if (MODE == 1) {
                    short4v pk;
                    pk.x = (short)f2bf(w * (acc[mi][0][j] + bias_n[0]));
                    pk.y = (short)f2bf(w * (acc[mi][1][j] + bias_n[1]));
                    pk.z = (short)f2bf(w * (acc[mi][2][j] + bias_n[2]));
                    pk.w = (short)f2bf(w * (acc[mi][3][j] + bias_n[3]));
                    *(short4v*)((unsigned short*)ywv + (size_t)oi * FN + n0 + wn * 64 + frow * 4) = pk;
                } else {
                    f32x4 pk;
                    pk.x = w * (acc[mi][0][j] + bias_n[0]);
                    pk.y = w * (acc[mi][1][j] + bias_n[1]);
                    pk.z = w * (acc[mi][2][j] + bias_n[2]);
                    pk.w = w * (acc[mi][3][j] + bias_n[3]);
                    *(f32x4*)((float*)ywv + (size_t)oi * FN + n0 + wn * 64 + frow * 4) = pk;
                }
            }
        }
    }
}

// ---------------- combine: out[t] = unperm(yw[2t] + yw[2t+1]) ----------------
__global__ __launch_bounds__(256) void k_combine_bf(const unsigned short* __restrict__ yw,
                                                    float* __restrict__ out)
{
    __shared__ float ls[FN];
    int t = blockIdx.x, i = threadIdx.x;
    const unsigned* r0 = (const unsigned*)(yw + (size_t)(2 * t) * FN);
    const unsigned* r1 = (const unsigned*)(yw + (size_t)(2 * t + 1) * FN);
    unsigned a0 = r0[2 * i], a1 = r0[2 * i + 1];
    unsigned c0 = r1[2 * i], c1 = r1[2 * i + 1];
    float s0 = bf2f((unsigned short)(a0 & 0xffff)) + bf2f((unsigned short)(c0 & 0xffff));
    float s1 = bf2f((unsigned short)(a0 >> 16))    + bf2f((unsigned short)(c0 >> 16));
    float s2 = bf2f((unsigned short)(a1 & 0xffff)) + bf2f((unsigned short)(c1 & 0xffff));
    float s3 = bf2f((unsigned short)(a1 >> 16))    + bf2f((unsigned short)(c1 >> 16));
    int base = (i >> 4) * 64 + (i & 15);           // wn*64 + frow
    ls[base +  0] = s0;
    ls[base + 16] = s1;
    ls[base + 32] = s2;
    ls[base + 48] = s3;
    __syncthreads();
    ((f32x4*)(out + (size_t)t * FN))[i] = ((const f32x4*)ls)[i];
}

__global__ __launch_bounds__(256) void k_combine_f32(const float* __restrict__ yw,
                                                     float* __restrict__ out)
{
    __shared__ float ls[FN];
    int t = blockIdx.x, i = threadIdx.x;
    f32x4 a = ((const f32x4*)(yw + (size_t)(2 * t) * FN))[i];
    f32x4 b = ((const f32x4*)(yw + (size_t)(2 * t + 1) * FN))[i];
    f32x4 s = a + b;
    int base = (i >> 4) * 64 + (i & 15);
    ls[base +  0] = s.x;
    ls[base + 16] = s.y;
    ls[base + 32] = s.z;
    ls[base + 48] = s.w;
    __syncthreads();
    ((f32x4*)(out + (size_t)t * FN))[i] = ((const f32x4*)ls)[i];
}

extern "C" void kernel_launch(void* const* d_in, const int* in_sizes, int n_in,
                              void* d_out, int out_size, void* d_ws, size_t ws_size,
                              hipStream_t stream)
{
    const float* x   = (const float*)d_in[0];
    const float* We  = (const float*)d_in[1];
    const float* beb = (const float*)d_in[2];
    const float* Wg  = (const float*)d_in[3];
    const float* bg  = (const float*)d_in[4];
    float* out = (float*)d_out;

    char* ws = (char*)d_ws;
    unsigned short* xb = (unsigned short*)ws;                        // 16 MB
    unsigned short* Wb = (unsigned short*)(ws + (size_t)(16 << 20)); // 16 MB
    size_t off = (size_t)(32 << 20);
    int*   seg      = (int*)(ws + off);   off += 256;
    int*   blockcnt = (int*)(ws + off);   off += HB * NE * 4;
    int*   basebuf  = (int*)(ws + off);   off += HB * NE * 4;
    int*   meta_e   = (int*)(ws + off);   off += (size_t)NTOK * 2 * 4;
    float* meta_w   = (float*)(ws + off); off += (size_t)NTOK * 2 * 4;
    int*   ridxb    = (int*)(ws + off);   off += (size_t)NTOK * 2 * 4;
    float* rwb      = (float*)(ws + off); off += (size_t)NTOK * 2 * 4;
    void*  yw       = (void*)(ws + ((off + 255) & ~(size_t)255));
    size_t yw_base  = (size_t)((off + 255) & ~(size_t)255);

    // pick epilogue mode from available scratch (host-side, deterministic).
    int mode;
    if (ws_size >= yw_base + (size_t)NTOK * 2 * FN * 2) mode = 1;       // bf16 yw (32 MB)
    else if (ws_size >= yw_base + (size_t)NTOK * 2 * FN * 4) mode = 2;  // f32 yw (64 MB)
    else mode = 0;                                                      // atomic fallback

    k_gate<<<NTOK / 4, 256, 0, stream>>>(x, Wg, bg, xb, meta_e, meta_w);
    k_convw<<<(NE * FN * DK / 4) / 256, 256, 0, stream>>>(We, Wb);
    k_hist<<<HB, 256, 0, stream>>>(meta_e, blockcnt);
    k_scan<<<1, 64, 0, stream>>>(blockcnt, seg, basebuf);
    k_scatter<<<HB, 256, 0, stream>>>(meta_e, meta_w, basebuf, ridxb, rwb);

    const int nblk = NE * (FN / BN) * MT;   // 8 experts x 4 n-tiles x 52 m-tiles
    if (mode == 1) {
        k_gemm<1><<<nblk, 512, 0, stream>>>(xb, Wb, beb, seg, ridxb, rwb, out, yw);
        k_combine_bf<<<NTOK, 256, 0, stream>>>((const unsigned short*)yw, out);
    } else if (mode == 2) {
        k_gemm<2><<<nblk, 512, 0, stream>>>(xb, Wb, beb, seg, ridxb, rwb, out, yw);
        k_combine_f32<<<NTOK, 256, 0, stream>>>((const float*)yw, out);
    } else {
        hipMemsetAsync(d_out, 0, (size_t)NTOK * FN * 4, stream);
        k_gemm<0><<<nblk, 512, 0, stream>>>(xb, Wb, beb, seg, ridxb, rwb, out, yw);
    }
}

// Round 10
// 87.416 us; speedup vs baseline: 1.0095x; 1.0095x over previous
//
#include <hip/hip_runtime.h>
#include <hip/hip_bf16.h>
#include <stdint.h>

#define NE 8
#define DK 1024
#define FN 1024
#define NTOK 8192

#define BN 256
#define BK 64
#define NIT (DK / BK)

#define HB 32
#define EPB (NTOK * 2 / HB)

// LDS map per buffer: A [320 rows x 128B] @0 (40960B), B-kh0 @40960 (16384B),
// B-kh1 @57344 (16384B); buffer stride 73728B; 2 buffers = 144KB.
#define BUFS 73728
#define BOFF 40960

typedef __attribute__((ext_vector_type(4))) float f32x4;
typedef __attribute__((ext_vector_type(8))) short short8;
typedef __attribute__((ext_vector_type(4))) short short4v;

__device__ __forceinline__ unsigned short f2bf(float f) {
    union { float f; unsigned u; } v; v.f = f;
    unsigned r = v.u;
    unsigned lsb = (r >> 16) & 1u;
    r += 0x7fffu + lsb;
    return (unsigned short)(r >> 16);
}
__device__ __forceinline__ float bf2f(unsigned short u) {
    union { unsigned u; float f; } v; v.u = ((unsigned)u) << 16;
    return v.f;
}

// ---------------- gating + x -> bf16 conversion (one wave per token) ---------
__global__ __launch_bounds__(256) void k_gate(const float* __restrict__ x,
    const float* __restrict__ Wg, const float* __restrict__ bg,
    unsigned short* __restrict__ xb, int* __restrict__ meta_e,
    float* __restrict__ meta_w)
{
    const int lane = threadIdx.x & 63;
    const int t = blockIdx.x * 4 + (threadIdx.x >> 6);

    const f32x4* xr = (const f32x4*)(x + (size_t)t * DK);
    f32x4 xv[4];
#pragma unroll
    for (int c = 0; c < 4; ++c) xv[c] = xr[lane + 64 * c];

    short4v* xbo = (short4v*)(xb + (size_t)t * DK);
#pragma unroll
    for (int c = 0; c < 4; ++c) {
        short4v b;
        b.x = (short)f2bf(xv[c].x); b.y = (short)f2bf(xv[c].y);
        b.z = (short)f2bf(xv[c].z); b.w = (short)f2bf(xv[c].w);
        xbo[lane + 64 * c] = b;
    }

    float acc[NE];
#pragma unroll
    for (int e = 0; e < NE; ++e) {
        const f32x4* wr = (const f32x4*)(Wg + e * DK);
        float a = 0.f;
#pragma unroll
        for (int c = 0; c < 4; ++c) {
            f32x4 wv = wr[lane + 64 * c];
            a += xv[c].x * wv.x + xv[c].y * wv.y + xv[c].z * wv.z + xv[c].w * wv.w;
        }
        acc[e] = a;
    }
#pragma unroll
    for (int e = 0; e < NE; ++e) {
        float a = acc[e];
#pragma unroll
        for (int off = 32; off > 0; off >>= 1) a += __shfl_xor(a, off, 64);
        acc[e] = a;
    }
    if (lane == 0) {
        float v[NE];
#pragma unroll
        for (int e = 0; e < NE; ++e) v[e] = acc[e] + bg[e];
        int b0 = 0; float m0 = v[0];
#pragma unroll
        for (int e = 1; e < NE; ++e) if (v[e] > m0) { m0 = v[e]; b0 = e; }
        int b1 = -1; float m1 = -3.4e38f;
#pragma unroll
        for (int e = 0; e < NE; ++e) if (e != b0 && v[e] > m1) { m1 = v[e]; b1 = e; }
        float r = expf(m1 - m0);
        float s = 1.f + r;
        meta_e[2 * t] = b0; meta_e[2 * t + 1] = b1;
        meta_w[2 * t] = 1.f / s; meta_w[2 * t + 1] = r / s;
    }
}

// ---------------- W -> bf16 ---------------------------------------------------
__global__ __launch_bounds__(256) void k_convw(const float* __restrict__ W,
                                               unsigned short* __restrict__ Wb)
{
    int i = blockIdx.x * 256 + threadIdx.x;
    f32x4 v = ((const f32x4*)W)[i];
    short4v b;
    b.x = (short)f2bf(v.x); b.y = (short)f2bf(v.y);
    b.z = (short)f2bf(v.z); b.w = (short)f2bf(v.w);
    ((short4v*)Wb)[i] = b;
}

// ---------------- per-block histogram (LDS atomics only) ---------------------
__global__ __launch_bounds__(256) void k_hist(const int* __restrict__ meta_e,
                                              int* __restrict__ blockcnt)
{
    __shared__ int lh[NE];
    if (threadIdx.x < NE) lh[threadIdx.x] = 0;
    __syncthreads();
    int base = blockIdx.x * EPB;
#pragma unroll
    for (int k = 0; k < EPB / 256; ++k)
        atomicAdd(&lh[meta_e[base + k * 256 + threadIdx.x]], 1);
    __syncthreads();
    if (threadIdx.x < NE) blockcnt[blockIdx.x * NE + threadIdx.x] = lh[threadIdx.x];
}

// ---------------- scan: expert segs + per-block bases ------------------------
__global__ void k_scan(const int* __restrict__ blockcnt, int* __restrict__ seg,
                       int* __restrict__ base)
{
    __shared__ int pre[HB][NE];
    __shared__ int colsum[NE];
    __shared__ int segstart[NE];
    int tid = threadIdx.x;
    if (tid < NE) {
        int run = 0;
        for (int b = 0; b < HB; ++b) { pre[b][tid] = run; run += blockcnt[b * NE + tid]; }
        colsum[tid] = run;
    }
    __syncthreads();
    if (tid == 0) {
        int s = 0;
        for (int e = 0; e < NE; ++e) { segstart[e] = s; seg[e] = s; s += colsum[e]; }
        seg[NE] = s;
    }
    __syncthreads();
    for (int i = tid; i < HB * NE; i += 64) {
        int b = i / NE, e = i % NE;
        base[i] = segstart[e] + pre[b][e];
    }
}

// ---------------- scatter: ridx[p] = 2t+k (orig slot), rw[p] = weight --------
__global__ __launch_bounds__(256) void k_scatter(const int* __restrict__ meta_e,
    const float* __restrict__ meta_w, const int* __restrict__ base,
    int* __restrict__ ridx, float* __restrict__ rw)
{
    __shared__ int lh[NE];
    __shared__ int bb[NE];
    if (threadIdx.x < NE) {
        lh[threadIdx.x] = 0;
        bb[threadIdx.x] = base[blockIdx.x * NE + threadIdx.x];
    }
    __syncthreads();
    int bs = blockIdx.x * EPB;
#pragma unroll
    for (int k = 0; k < EPB / 256; ++k) {
        int i = bs + k * 256 + threadIdx.x;
        int e = meta_e[i];
        int r = atomicAdd(&lh[e], 1);
        int p = bb[e] + r;
        ridx[p] = i;
        rw[p] = meta_w[i];
    }
}

// ---------------- grouped GEMM: balanced 8-tiles/expert, 4-phase pipeline ----
// Grid = 8 e x 4 n x 8 mt = 256 blocks (1.0 rounds, balanced).
// Per-expert tile rows l = ceil(L/8) (~257); per-wave h = ceil8(l/2) <= 144
// -> acc[9][4] = 144 AGPR (+ ~110 VGPR) = fits 2 waves/SIMD (the R9 defect:
// acc[10][4]=160+128 VGPR = 288 regs -> 1 wave/SIMD, occupancy 15%).
// LDS addrs collapse to base+immediate: a_off = a_base[kk]+mi*2048,
// b_off = b_base[kk]+ni*1024 (mi*16,ni*16 preserve swizzle bits).
// Schedule/gates identical to R9 (proof in comments below).
template <int MODE>
__global__ __launch_bounds__(512, 2) void k_gemm(const unsigned short* __restrict__ xb,
    const unsigned short* __restrict__ Wb, const float* __restrict__ be,
    const int* __restrict__ seg, const int* __restrict__ ridx,
    const float* __restrict__ rw, float* __restrict__ out, void* __restrict__ ywv)
{
    __shared__ char Lds[2 * BUFS];   // 144 KB

    const int bid = blockIdx.x;
    const int e = bid & 7;                       // XCD-pinned expert
    const int n0 = ((bid >> 3) & 3) * BN;
    const int mt = bid >> 5;                     // 0..7
    const int s0 = seg[e];
    const int L = seg[e + 1] - s0;
    const int lpt = (L + 7) >> 3;                // rows per m-tile
    int m0 = mt * lpt;
    const int m_end = (m0 + lpt < L) ? (m0 + lpt) : L;
    if (m0 >= m_end) return;

    const int tid = threadIdx.x;
    const int lane = tid & 63;
    const int wid = tid >> 6;
    const int wm = wid >> 2, wn = wid & 3;       // 2 x 4 wave grid
    const int frow = lane & 15;
    const int fq = lane >> 4;

    // B staging (loop-invariant): instr c covers rows c*128 + tid/4
    const int bgr = ((tid & 3) ^ ((tid >> 3) & 3)) * 8;
    const unsigned short* bsrc[2];
#pragma unroll
    for (int c = 0; c < 2; ++c) {
        int r = c * 128 + (tid >> 2);
        bsrc[c] = Wb + ((size_t)e * FN + n0 + r) * DK + bgr;
    }
    // B read bases (loop-invariant): r = wn*64 + frow (+ni*16)
    int b_base[2];
    {
        int r = wn * 64 + frow;
        int sl = fq ^ ((frow >> 1) & 3);
#pragma unroll
        for (int kk = 0; kk < 2; ++kk)
            b_base[kk] = BOFF + kk * 16384 + r * 64 + sl * 16;
    }

    char* LB = (char*)Lds;
    const int ag = ((tid & 7) ^ ((tid >> 3) & 7)) * 8;

    float bias_n[4];
#pragma unroll
    for (int ni = 0; ni < 4; ++ni)
        bias_n[ni] = be[e * FN + n0 + wn * 64 + ni * 16 + frow];

    // chunk loop (single iteration unless an expert holds >2304 rows)
    for (; m0 < m_end; m0 += 288) {
        const int rows = (m_end - m0 < 288) ? (m_end - m0) : 288;
        const int h = ((rows + 15) >> 4) << 3;       // per-wave rows, mult of 8

        // A staging: instr c covers rows c*64 + tid/8 (clamped)
        const unsigned short* asrc[5];
#pragma unroll
        for (int c = 0; c < 5; ++c) {
            int r = c * 64 + (tid >> 3);
            int idx = m0 + r; if (idx >= m_end) idx = m_end - 1;
            asrc[c] = xb + (size_t)(ridx[s0 + idx] >> 1) * DK + ag;
        }
        // A read bases: row = wm*h + frow (+mi*16); h%8==0 so row&7 == frow&7
        int a_base[2];
#pragma unroll
        for (int kk = 0; kk < 2; ++kk)
            a_base[kk] = (wm * h + frow) * 128 + (((kk * 4 + fq) ^ (frow & 7)) * 16);

        f32x4 acc[9][4];
#pragma unroll
        for (int i = 0; i < 9; ++i)
#pragma unroll
            for (int j = 0; j < 4; ++j) acc[i][j] = f32x4{0.f, 0.f, 0.f, 0.f};

        auto STAGE_A = [&](int buf, int kt) {
            const int ko = kt * BK;
            char* dst = LB + buf * BUFS + wid * 1024;
#pragma unroll
            for (int c = 0; c < 5; ++c)
                __builtin_amdgcn_global_load_lds(
                    (const __attribute__((address_space(1))) void*)(asrc[c] + ko),
                    (__attribute__((address_space(3))) void*)(dst + c * 8192), 16, 0, 0);
        };
        auto STAGE_B = [&](int buf, int kt, int kh) {
            const int ko = kt * BK + kh * 32;
            char* dst = LB + buf * BUFS + BOFF + kh * 16384 + wid * 1024;
#pragma unroll
            for (int c = 0; c < 2; ++c)
                __builtin_amdgcn_global_load_lds(
                    (const __attribute__((address_space(1))) void*)(bsrc[c] + ko),
                    (__attribute__((address_space(3))) void*)(dst + c * 8192), 16, 0, 0);
        };

#define GATE(N) do { asm volatile("s_waitcnt vmcnt(" #N ")" ::: "memory"); \
                     __builtin_amdgcn_s_barrier(); \
                     __builtin_amdgcn_sched_barrier(0); } while (0)
#define BARP  do { __builtin_amdgcn_s_barrier(); \
                   __builtin_amdgcn_sched_barrier(0); } while (0)
#define LGKM0 do { asm volatile("s_waitcnt lgkmcnt(0)" ::: "memory"); \
                   __builtin_amdgcn_sched_barrier(0); } while (0)
#define MFMA45(AF, BF, MLO, CNT) do { \
    __builtin_amdgcn_s_setprio(1); \
    _Pragma("unroll") \
    for (int mi = 0; mi < (CNT); ++mi) { \
        _Pragma("unroll") \
        for (int ni = 0; ni < 4; ++ni) \
            acc[(MLO) + mi][ni] = __builtin_amdgcn_mfma_f32_16x16x32_bf16( \
                AF[mi], BF[ni], acc[(MLO) + mi][ni], 0, 0, 0); \
    } \
    __builtin_amdgcn_s_setprio(0); } while (0)

        // prologue: tile 0 -> buf 0 (issue order [A:5][B0:2][B1:2] = 9)
        STAGE_A(0, 0); STAGE_B(0, 0, 0); STAGE_B(0, 0, 1);
        __builtin_amdgcn_sched_barrier(0);

        // vmcnt proof (in-order retire); per tile issue = [A:5@P0][B0:2@P1][B1:2@P2]
        // P0(t) GATE(2): outstanding A(t)5+B0(t)2+B1(t)2=9 -> retires A+B0.
        // P2(t) GATE(7): outstanding B1(t)2+A(t+1)5+B0(t+1)2=9 -> retires B1(t).
        // Last tile: GATE(0) at P2. WAR: every wave lgkm0s its reads before the
        // next barrier, so post-barrier stages never overwrite in-flight reads.
        for (int t = 0; t < NIT; ++t) {
            const int b = t & 1;
            const char* Cb = LB + b * BUFS;
            const bool st = (t + 1 < NIT);
            short8 b0f[4], b1f[4], af[5];

            // ---- P0: gate A(t)+B0(t); kk0 x mi 0-4 ----
            GATE(2);
#pragma unroll
            for (int ni = 0; ni < 4; ++ni)
                b0f[ni] = *(const short8*)(Cb + b_base[0] + ni * 1024);
#pragma unroll
            for (int mi = 0; mi < 5; ++mi)
                af[mi] = *(const short8*)(Cb + a_base[0] + mi * 2048);
            if (st) STAGE_A(b ^ 1, t + 1);
            LGKM0;
            MFMA45(af, b0f, 0, 5);

            // ---- P1: kk0 x mi 5-8 ----
            BARP;
#pragma unroll
            for (int mi = 0; mi < 4; ++mi)
                af[mi] = *(const short8*)(Cb + a_base[0] + (5 + mi) * 2048);
            if (st) STAGE_B(b ^ 1, t + 1, 0);
            LGKM0;
            MFMA45(af, b0f, 5, 4);

            // ---- P2: gate B1(t); kk1 x mi 0-4 ----
            if (st) { GATE(7); } else { GATE(0); }
#pragma unroll
            for (int ni = 0; ni < 4; ++ni)
                b1f[ni] = *(const short8*)(Cb + b_base[1] + ni * 1024);
#pragma unroll
            for (int mi = 0; mi < 5; ++mi)
                af[mi] = *(const short8*)(Cb + a_base[1] + mi * 2048);
            if (st) STAGE_B(b ^ 1, t + 1, 1);
            LGKM0;
            MFMA45(af, b1f, 0, 5);

            // ---- P3: kk1 x mi 5-8 ----
            BARP;
#pragma unroll
            for (int mi = 0; mi < 4; ++mi)
                af[mi] = *(const short8*)(Cb + a_base[1] + (5 + mi) * 2048);
            LGKM0;
            MFMA45(af, b1f, 5, 4);
        }
#undef GATE
#undef BARP
#undef LGKM0
#undef MFMA45

        // epilogue: D col = lane&15, row = (lane>>4)*4 + j
        const int fq4 = fq * 4;
#pragma unroll
        for (int mi = 0; mi < 9; ++mi) {
#pragma unroll
            for (int j = 0; j < 4; ++j) {
                int lr = mi * 16 + fq4 + j;          // row within wave slice
                int idx = m0 + wm * h + lr;
                if (lr < h && idx < m_end) {
                    float w = rw[s0 + idx];
                    int oi = ridx[s0 + idx];
                    if (MODE == 0) {
                        float* orow = out + (size_t)(oi >> 1) * FN + n0 + wn * 64 + frow;
#pragma unroll
                        for (int ni = 0; ni < 4; ++ni)
                            atomicAdd(orow + ni * 16, w * (acc[mi][ni][j] + bias_n[ni]));
                    } else if (MODE == 1) {
                        short4v pk;
                        pk.x = (short)f2bf(w * (acc[mi][0][j] + bias_n[0]));
                        pk.y = (short)f2bf(w * (acc[mi][1][j] + bias_n[1]));
                        pk.z = (short)f2bf(w * (acc[mi][2][j] + bias_n[2]));
                        pk.w = (short)f2bf(w * (acc[mi][3][j] + bias_n[3]));
                        *(short4v*)((unsigned short*)ywv + (size_t)oi * FN + n0 + wn * 64 + frow * 4) = pk;
                    } else {
                        f32x4 pk;
                        pk.x = w * (acc[mi][0][j] + bias_n[0]);
                        pk.y = w * (acc[mi][1][j] + bias_n[1]);
                        pk.z = w * (acc[mi][2][j] + bias_n[2]);
                        pk.w = w * (acc[mi][3][j] + bias_n[3]);
                        *(f32x4*)((float*)ywv + (size_t)oi * FN + n0 + wn * 64 + frow * 4) = pk;
                    }
                }
            }
        }
    }
}

// ---------------- combine: out[t] = unperm(yw[2t] + yw[2t+1]) ----------------
__global__ __launch_bounds__(256) void k_combine_bf(const unsigned short* __restrict__ yw,
                                                    float* __restrict__ out)
{
    __shared__ float ls[FN];
    int t = blockIdx.x, i = threadIdx.x;
    const unsigned* r0 = (const unsigned*)(yw + (size_t)(2 * t) * FN);
    const unsigned* r1 = (const unsigned*)(yw + (size_t)(2 * t + 1) * FN);
    unsigned a0 = r0[2 * i], a1 = r0[2 * i + 1];
    unsigned c0 = r1[2 * i], c1 = r1[2 * i + 1];
    float s0 = bf2f((unsigned short)(a0 & 0xffff)) + bf2f((unsigned short)(c0 & 0xffff));
    float s1 = bf2f((unsigned short)(a0 >> 16))    + bf2f((unsigned short)(c0 >> 16));
    float s2 = bf2f((unsigned short)(a1 & 0xffff)) + bf2f((unsigned short)(c1 & 0xffff));
    float s3 = bf2f((unsigned short)(a1 >> 16))    + bf2f((unsigned short)(c1 >> 16));
    int base = (i >> 4) * 64 + (i & 15);           // wn*64 + frow
    ls[base +  0] = s0;
    ls[base + 16] = s1;
    ls[base + 32] = s2;
    ls[base + 48] = s3;
    __syncthreads();
    ((f32x4*)(out + (size_t)t * FN))[i] = ((const f32x4*)ls)[i];
}

__global__ __launch_bounds__(256) void k_combine_f32(const float* __restrict__ yw,
                                                     float* __restrict__ out)
{
    __shared__ float ls[FN];
    int t = blockIdx.x, i = threadIdx.x;
    f32x4 a = ((const f32x4*)(yw + (size_t)(2 * t) * FN))[i];
    f32x4 b = ((const f32x4*)(yw + (size_t)(2 * t + 1) * FN))[i];
    f32x4 s = a + b;
    int base = (i >> 4) * 64 + (i & 15);
    ls[base +  0] = s.x;
    ls[base + 16] = s.y;
    ls[base + 32] = s.z;
    ls[base + 48] = s.w;
    __syncthreads();
    ((f32x4*)(out + (size_t)t * FN))[i] = ((const f32x4*)ls)[i];
}

extern "C" void kernel_launch(void* const* d_in, const int* in_sizes, int n_in,
                              void* d_out, int out_size, void* d_ws, size_t ws_size,
                              hipStream_t stream)
{
    const float* x   = (const float*)d_in[0];
    const float* We  = (const float*)d_in[1];
    const float* beb = (const float*)d_in[2];
    const float* Wg  = (const float*)d_in[3];
    const float* bg  = (const float*)d_in[4];
    float* out = (float*)d_out;

    char* ws = (char*)d_ws;
    unsigned short* xb = (unsigned short*)ws;                        // 16 MB
    unsigned short* Wb = (unsigned short*)(ws + (size_t)(16 << 20)); // 16 MB
    size_t off = (size_t)(32 << 20);
    int*   seg      = (int*)(ws + off);   off += 256;
    int*   blockcnt = (int*)(ws + off);   off += HB * NE * 4;
    int*   basebuf  = (int*)(ws + off);   off += HB * NE * 4;
    int*   meta_e   = (int*)(ws + off);   off += (size_t)NTOK * 2 * 4;
    float* meta_w   = (float*)(ws + off); off += (size_t)NTOK * 2 * 4;
    int*   ridxb    = (int*)(ws + off);   off += (size_t)NTOK * 2 * 4;
    float* rwb      = (float*)(ws + off); off += (size_t)NTOK * 2 * 4;
    void*  yw       = (void*)(ws + ((off + 255) & ~(size_t)255));
    size_t yw_base  = (size_t)((off + 255) & ~(size_t)255);

    // pick epilogue mode from available scratch (host-side, deterministic).
    int mode;
    if (ws_size >= yw_base + (size_t)NTOK * 2 * FN * 2) mode = 1;       // bf16 yw (32 MB)
    else if (ws_size >= yw_base + (size_t)NTOK * 2 * FN * 4) mode = 2;  // f32 yw (64 MB)
    else mode = 0;                                                      // atomic fallback

    k_gate<<<NTOK / 4, 256, 0, stream>>>(x, Wg, bg, xb, meta_e, meta_w);
    k_convw<<<(NE * FN * DK / 4) / 256, 256, 0, stream>>>(We, Wb);
    k_hist<<<HB, 256, 0, stream>>>(meta_e, blockcnt);
    k_scan<<<1, 64, 0, stream>>>(blockcnt, seg, basebuf);
    k_scatter<<<HB, 256, 0, stream>>>(meta_e, meta_w, basebuf, ridxb, rwb);

    const int nblk = NE * (FN / BN) * 8;   // 8 experts x 4 n-tiles x 8 m-tiles = 256
    if (mode == 1) {
        k_gemm<1><<<nblk, 512, 0, stream>>>(xb, Wb, beb, seg, ridxb, rwb, out, yw);
        k_combine_bf<<<NTOK, 256, 0, stream>>>((const unsigned short*)yw, out);
    } else if (mode == 2) {
        k_gemm<2><<<nblk, 512, 0, stream>>>(xb, Wb, beb, seg, ridxb, rwb, out, yw);
        k_combine_f32<<<NTOK, 256, 0, stream>>>((const float*)yw, out);
    } else {
        hipMemsetAsync(d_out, 0, (size_t)NTOK * FN * 4, stream);
        k_gemm<0><<<nblk, 512, 0, stream>>>(xb, Wb, beb, seg, ridxb, rwb, out, yw);
    }
}

// Round 11
// 85.576 us; speedup vs baseline: 1.0312x; 1.0215x over previous
//
#include <hip/hip_runtime.h>
#include <hip/hip_bf16.h>
#include <stdint.h>

#define NE 8
#define DK 1024
#define FN 1024
#define NTOK 8192

#define BN 256
#define BK 64
#define NIT (DK / BK)
#define H 144            // fixed per-wave rows (2 waves of M, 288-row block)

#define HB 32
#define EPB (NTOK * 2 / HB)

// LDS map per buffer: A [320 rows x 128B] @0 (40960B; rows 288..319 = clamp
// padding), B-kh0 @40960 (16384B), B-kh1 @57344 (16384B); stride 73728B x2.
#define BUFS 73728
#define BOFF 40960

typedef __attribute__((ext_vector_type(4))) float f32x4;
typedef __attribute__((ext_vector_type(8))) short short8;
typedef __attribute__((ext_vector_type(4))) short short4v;

__device__ __forceinline__ unsigned short f2bf(float f) {
    union { float f; unsigned u; } v; v.f = f;
    unsigned r = v.u;
    unsigned lsb = (r >> 16) & 1u;
    r += 0x7fffu + lsb;
    return (unsigned short)(r >> 16);
}
__device__ __forceinline__ float bf2f(unsigned short u) {
    union { unsigned u; float f; } v; v.u = ((unsigned)u) << 16;
    return v.f;
}

// ---------------- gating + x -> bf16 conversion (one wave per token) ---------
__global__ __launch_bounds__(256) void k_gate(const float* __restrict__ x,
    const float* __restrict__ Wg, const float* __restrict__ bg,
    unsigned short* __restrict__ xb, int* __restrict__ meta_e,
    float* __restrict__ meta_w)
{
    const int lane = threadIdx.x & 63;
    const int t = blockIdx.x * 4 + (threadIdx.x >> 6);

    const f32x4* xr = (const f32x4*)(x + (size_t)t * DK);
    f32x4 xv[4];
#pragma unroll
    for (int c = 0; c < 4; ++c) xv[c] = xr[lane + 64 * c];

    short4v* xbo = (short4v*)(xb + (size_t)t * DK);
#pragma unroll
    for (int c = 0; c < 4; ++c) {
        short4v b;
        b.x = (short)f2bf(xv[c].x); b.y = (short)f2bf(xv[c].y);
        b.z = (short)f2bf(xv[c].z); b.w = (short)f2bf(xv[c].w);
        xbo[lane + 64 * c] = b;
    }

    float acc[NE];
#pragma unroll
    for (int e = 0; e < NE; ++e) {
        const f32x4* wr = (const f32x4*)(Wg + e * DK);
        float a = 0.f;
#pragma unroll
        for (int c = 0; c < 4; ++c) {
            f32x4 wv = wr[lane + 64 * c];
            a += xv[c].x * wv.x + xv[c].y * wv.y + xv[c].z * wv.z + xv[c].w * wv.w;
        }
        acc[e] = a;
    }
#pragma unroll
    for (int e = 0; e < NE; ++e) {
        float a = acc[e];
#pragma unroll
        for (int off = 32; off > 0; off >>= 1) a += __shfl_xor(a, off, 64);
        acc[e] = a;
    }
    if (lane == 0) {
        float v[NE];
#pragma unroll
        for (int e = 0; e < NE; ++e) v[e] = acc[e] + bg[e];
        int b0 = 0; float m0 = v[0];
#pragma unroll
        for (int e = 1; e < NE; ++e) if (v[e] > m0) { m0 = v[e]; b0 = e; }
        int b1 = -1; float m1 = -3.4e38f;
#pragma unroll
        for (int e = 0; e < NE; ++e) if (e != b0 && v[e] > m1) { m1 = v[e]; b1 = e; }
        float r = expf(m1 - m0);
        float s = 1.f + r;
        meta_e[2 * t] = b0; meta_e[2 * t + 1] = b1;
        meta_w[2 * t] = 1.f / s; meta_w[2 * t + 1] = r / s;
    }
}

// ---------------- W -> bf16 ---------------------------------------------------
__global__ __launch_bounds__(256) void k_convw(const float* __restrict__ W,
                                               unsigned short* __restrict__ Wb)
{
    int i = blockIdx.x * 256 + threadIdx.x;
    f32x4 v = ((const f32x4*)W)[i];
    short4v b;
    b.x = (short)f2bf(v.x); b.y = (short)f2bf(v.y);
    b.z = (short)f2bf(v.z); b.w = (short)f2bf(v.w);
    ((short4v*)Wb)[i] = b;
}

// ---------------- per-block histogram (LDS atomics only) ---------------------
__global__ __launch_bounds__(256) void k_hist(const int* __restrict__ meta_e,
                                              int* __restrict__ blockcnt)
{
    __shared__ int lh[NE];
    if (threadIdx.x < NE) lh[threadIdx.x] = 0;
    __syncthreads();
    int base = blockIdx.x * EPB;
#pragma unroll
    for (int k = 0; k < EPB / 256; ++k)
        atomicAdd(&lh[meta_e[base + k * 256 + threadIdx.x]], 1);
    __syncthreads();
    if (threadIdx.x < NE) blockcnt[blockIdx.x * NE + threadIdx.x] = lh[threadIdx.x];
}

// ---------------- scan: expert segs + per-block bases ------------------------
__global__ void k_scan(const int* __restrict__ blockcnt, int* __restrict__ seg,
                       int* __restrict__ base)
{
    __shared__ int pre[HB][NE];
    __shared__ int colsum[NE];
    __shared__ int segstart[NE];
    int tid = threadIdx.x;
    if (tid < NE) {
        int run = 0;
        for (int b = 0; b < HB; ++b) { pre[b][tid] = run; run += blockcnt[b * NE + tid]; }
        colsum[tid] = run;
    }
    __syncthreads();
    if (tid == 0) {
        int s = 0;
        for (int e = 0; e < NE; ++e) { segstart[e] = s; seg[e] = s; s += colsum[e]; }
        seg[NE] = s;
    }
    __syncthreads();
    for (int i = tid; i < HB * NE; i += 64) {
        int b = i / NE, e = i % NE;
        base[i] = segstart[e] + pre[b][e];
    }
}

// ---------------- scatter: ridx[p] = 2t+k (orig slot), rw[p] = weight --------
__global__ __launch_bounds__(256) void k_scatter(const int* __restrict__ meta_e,
    const float* __restrict__ meta_w, const int* __restrict__ base,
    int* __restrict__ ridx, float* __restrict__ rw)
{
    __shared__ int lh[NE];
    __shared__ int bb[NE];
    if (threadIdx.x < NE) {
        lh[threadIdx.x] = 0;
        bb[threadIdx.x] = base[blockIdx.x * NE + threadIdx.x];
    }
    __syncthreads();
    int bs = blockIdx.x * EPB;
#pragma unroll
    for (int k = 0; k < EPB / 256; ++k) {
        int i = bs + k * 256 + threadIdx.x;
        int e = meta_e[i];
        int r = atomicAdd(&lh[e], 1);
        int p = bb[e] + r;
        ridx[p] = i;
        rw[p] = meta_w[i];
    }
}

// ---------------- grouped GEMM: balanced 8-tiles/expert, 4-phase pipeline ----
// Register budget is THE constraint (R10 lesson): acc[9][4]=144 AGPR demands
// arch VGPR <= 112 so 2 waves/SIMD fit (512-reg pool). Levers: 32-bit element
// offsets off SGPR bases (saves 7), fixed H=144 (constant addressing), bias
// loaded in epilogue, shared B-frag array across kk halves.
// Grid = 8e x 4n x 8mt = 256 blocks, balanced single round.
// Schedule/gates identical to R9/R10 (proof below).
template <int MODE>
__global__ __launch_bounds__(512, 2) void k_gemm(const unsigned short* __restrict__ xb,
    const unsigned short* __restrict__ Wb, const float* __restrict__ be,
    const int* __restrict__ seg, const int* __restrict__ ridx,
    const float* __restrict__ rw, float* __restrict__ out, void* __restrict__ ywv)
{
    __shared__ char Lds[2 * BUFS];   // 144 KB

    const int bid = blockIdx.x;
    const int e = bid & 7;                       // XCD-pinned expert
    const int n0 = ((bid >> 3) & 3) * BN;
    const int mt = bid >> 5;                     // 0..7
    const int s0 = seg[e];
    const int L = seg[e + 1] - s0;
    const int lpt = (L + 7) >> 3;                // rows per m-tile
    int m0 = mt * lpt;
    const int m_end = (m0 + lpt < L) ? (m0 + lpt) : L;
    if (m0 >= m_end) return;

    const int tid = threadIdx.x;
    const int lane = tid & 63;
    const int wid = tid >> 6;
    const int wm = wid >> 2, wn = wid & 3;       // 2 x 4 wave grid
    const int frow = lane & 15;
    const int fq = lane >> 4;

    // B staging offsets (32-bit elements off Wb): instr c covers rows c*128+tid/4
    const int bgr = ((tid & 3) ^ ((tid >> 3) & 3)) * 8;
    unsigned boff[2];
#pragma unroll
    for (int c = 0; c < 2; ++c)
        boff[c] = (((unsigned)(e * FN + n0 + c * 128 + (tid >> 2))) << 10) + bgr;

    // B read bases (loop-invariant)
    int b_base[2];
    {
        int r = wn * 64 + frow;
        int sl = fq ^ ((frow >> 1) & 3);
#pragma unroll
        for (int kk = 0; kk < 2; ++kk)
            b_base[kk] = BOFF + kk * 16384 + r * 64 + sl * 16;
    }
    // A read bases (H fixed -> constant-folded)
    int a_base[2];
#pragma unroll
    for (int kk = 0; kk < 2; ++kk)
        a_base[kk] = (wm * H + frow) * 128 + (((kk * 4 + fq) ^ (frow & 7)) * 16);

    char* LB = (char*)Lds;
    const int ag = ((tid & 7) ^ ((tid >> 3) & 7)) * 8;

    // chunk loop (single iteration unless an expert holds >2304 rows)
    for (; m0 < m_end; m0 += 288) {
        // A staging offsets (32-bit elements off xb): instr c rows c*64+tid/8
        unsigned aoff[5];
#pragma unroll
        for (int c = 0; c < 5; ++c) {
            int r = c * 64 + (tid >> 3);
            int idx = m0 + r; if (idx >= m_end) idx = m_end - 1;
            aoff[c] = (((unsigned)(ridx[s0 + idx] >> 1)) << 10) + ag;
        }

        f32x4 acc[9][4];
#pragma unroll
        for (int i = 0; i < 9; ++i)
#pragma unroll
            for (int j = 0; j < 4; ++j) acc[i][j] = f32x4{0.f, 0.f, 0.f, 0.f};

        auto STAGE_A = [&](int buf, int kt) {
            const unsigned ko = kt * BK;
            char* dst = LB + buf * BUFS + wid * 1024;
#pragma unroll
            for (int c = 0; c < 5; ++c)
                __builtin_amdgcn_global_load_lds(
                    (const __attribute__((address_space(1))) void*)(xb + aoff[c] + ko),
                    (__attribute__((address_space(3))) void*)(dst + c * 8192), 16, 0, 0);
        };
        auto STAGE_B = [&](int buf, int kt, int kh) {
            const unsigned ko = kt * BK + kh * 32;
            char* dst = LB + buf * BUFS + BOFF + kh * 16384 + wid * 1024;
#pragma unroll
            for (int c = 0; c < 2; ++c)
                __builtin_amdgcn_global_load_lds(
                    (const __attribute__((address_space(1))) void*)(Wb + boff[c] + ko),
                    (__attribute__((address_space(3))) void*)(dst + c * 8192), 16, 0, 0);
        };

#define GATE(N) do { asm volatile("s_waitcnt vmcnt(" #N ")" ::: "memory"); \
                     __builtin_amdgcn_s_barrier(); \
                     __builtin_amdgcn_sched_barrier(0); } while (0)
#define BARP  do { __builtin_amdgcn_s_barrier(); \
                   __builtin_amdgcn_sched_barrier(0); } while (0)
#define LGKM0 do { asm volatile("s_waitcnt lgkmcnt(0)" ::: "memory"); \
                   __builtin_amdgcn_sched_barrier(0); } while (0)
#define MFMA45(AF, BF, MLO, CNT) do { \
    __builtin_amdgcn_s_setprio(1); \
    _Pragma("unroll") \
    for (int mi = 0; mi < (CNT); ++mi) { \
        _Pragma("unroll") \
        for (int ni = 0; ni < 4; ++ni) \
            acc[(MLO) + mi][ni] = __builtin_amdgcn_mfma_f32_16x16x32_bf16( \
                AF[mi], BF[ni], acc[(MLO) + mi][ni], 0, 0, 0); \
    } \
    __builtin_amdgcn_s_setprio(0); } while (0)

        // prologue: tile 0 -> buf 0 (issue order [A:5][B0:2][B1:2] = 9)
        STAGE_A(0, 0); STAGE_B(0, 0, 0); STAGE_B(0, 0, 1);
        __builtin_amdgcn_sched_barrier(0);

        // vmcnt proof (in-order retire); per tile issue = [A:5@P0][B0:2@P1][B1:2@P2]
        // P0(t) GATE(2): outstanding A(t)5+B0(t)2+B1(t)2=9 -> retires A+B0.
        // P2(t) GATE(7): outstanding B1(t)2+A(t+1)5+B0(t+1)2=9 -> retires B1(t).
        // Last tile: GATE(0) at P2. WAR: every wave lgkm0s its reads before the
        // next barrier, so post-barrier stages never overwrite in-flight reads.
        for (int t = 0; t < NIT; ++t) {
            const int b = t & 1;
            const char* Cb = LB + b * BUFS;
            const bool st = (t + 1 < NIT);
            short8 bf[4], af[5];

            // ---- P0: gate A(t)+B0(t); kk0 x mi 0-4 ----
            GATE(2);
#pragma unroll
            for (int ni = 0; ni < 4; ++ni)
                bf[ni] = *(const short8*)(Cb + b_base[0] + ni * 1024);
#pragma unroll
            for (int mi = 0; mi < 5; ++mi)
                af[mi] = *(const short8*)(Cb + a_base[0] + mi * 2048);
            if (st) STAGE_A(b ^ 1, t + 1);
            LGKM0;
            MFMA45(af, bf, 0, 5);

            // ---- P1: kk0 x mi 5-8 ----
            BARP;
#pragma unroll
            for (int mi = 0; mi < 4; ++mi)
                af[mi] = *(const short8*)(Cb + a_base[0] + (5 + mi) * 2048);
            if (st) STAGE_B(b ^ 1, t + 1, 0);
            LGKM0;
            MFMA45(af, bf, 5, 4);

            // ---- P2: gate B1(t); kk1 x mi 0-4 (bf reused: b0 frags dead) ----
            if (st) { GATE(7); } else { GATE(0); }
#pragma unroll
            for (int ni = 0; ni < 4; ++ni)
                bf[ni] = *(const short8*)(Cb + b_base[1] + ni * 1024);
#pragma unroll
            for (int mi = 0; mi < 5; ++mi)
                af[mi] = *(const short8*)(Cb + a_base[1] + mi * 2048);
            if (st) STAGE_B(b ^ 1, t + 1, 1);
            LGKM0;
            MFMA45(af, bf, 0, 5);

            // ---- P3: kk1 x mi 5-8 ----
            BARP;
#pragma unroll
            for (int mi = 0; mi < 4; ++mi)
                af[mi] = *(const short8*)(Cb + a_base[1] + (5 + mi) * 2048);
            LGKM0;
            MFMA45(af, bf, 5, 4);
        }
#undef GATE
#undef BARP
#undef LGKM0
#undef MFMA45

        // epilogue: D col = lane&15, row = (lane>>4)*4 + j; bias loaded here
        float bias_n[4];
#pragma unroll
        for (int ni = 0; ni < 4; ++ni)
            bias_n[ni] = be[e * FN + n0 + wn * 64 + ni * 16 + frow];

        const int fq4 = fq * 4;
#pragma unroll
        for (int mi = 0; mi < 9; ++mi) {
#pragma unroll
            for (int j = 0; j < 4; ++j) {
                int lr = mi * 16 + fq4 + j;          // row within wave slice
                int idx = m0 + wm * H + lr;
                if (idx < m_end) {
                    float w = rw[s0 + idx];
                    int oi = ridx[s0 + idx];
                    if (MODE == 0) {
                        float* orow = out + (size_t)(oi >> 1) * FN + n0 + wn * 64 + frow;
#pragma unroll
                        for (int ni = 0; ni < 4; ++ni)
                            atomicAdd(orow + ni * 16, w * (acc[mi][ni][j] + bias_n[ni]));
                    } else if (MODE == 1) {
                        short4v pk;
                        pk.x = (short)f2bf(w * (acc[mi][0][j] + bias_n[0]));
                        pk.y = (short)f2bf(w * (acc[mi][1][j] + bias_n[1]));
                        pk.z = (short)f2bf(w * (acc[mi][2][j] + bias_n[2]));
                        pk.w = (short)f2bf(w * (acc[mi][3][j] + bias_n[3]));
                        *(short4v*)((unsigned short*)ywv + (size_t)oi * FN + n0 + wn * 64 + frow * 4) = pk;
                    } else {
                        f32x4 pk;
                        pk.x = w * (acc[mi][0][j] + bias_n[0]);
                        pk.y = w * (acc[mi][1][j] + bias_n[1]);
                        pk.z = w * (acc[mi][2][j] + bias_n[2]);
                        pk.w = w * (acc[mi][3][j] + bias_n[3]);
                        *(f32x4*)((float*)ywv + (size_t)oi * FN + n0 + wn * 64 + frow * 4) = pk;
                    }
                }
            }
        }
    }
}

// ---------------- combine: out[t] = unperm(yw[2t] + yw[2t+1]) ----------------
__global__ __launch_bounds__(256) void k_combine_bf(const unsigned short* __restrict__ yw,
                                                    float* __restrict__ out)
{
    __shared__ float ls[FN];
    int t = blockIdx.x, i = threadIdx.x;
    const unsigned* r0 = (const unsigned*)(yw + (size_t)(2 * t) * FN);
    const unsigned* r1 = (const unsigned*)(yw + (size_t)(2 * t + 1) * FN);
    unsigned a0 = r0[2 * i], a1 = r0[2 * i + 1];
    unsigned c0 = r1[2 * i], c1 = r1[2 * i + 1];
    float s0 = bf2f((unsigned short)(a0 & 0xffff)) + bf2f((unsigned short)(c0 & 0xffff));
    float s1 = bf2f((unsigned short)(a0 >> 16))    + bf2f((unsigned short)(c0 >> 16));
    float s2 = bf2f((unsigned short)(a1 & 0xffff)) + bf2f((unsigned short)(c1 & 0xffff));
    float s3 = bf2f((unsigned short)(a1 >> 16))    + bf2f((unsigned short)(c1 >> 16));
    int base = (i >> 4) * 64 + (i & 15);           // wn*64 + frow
    ls[base +  0] = s0;
    ls[base + 16] = s1;
    ls[base + 32] = s2;
    ls[base + 48] = s3;
    __syncthreads();
    ((f32x4*)(out + (size_t)t * FN))[i] = ((const f32x4*)ls)[i];
}

__global__ __launch_bounds__(256) void k_combine_f32(const float* __restrict__ yw,
                                                     float* __restrict__ out)
{
    __shared__ float ls[FN];
    int t = blockIdx.x, i = threadIdx.x;
    f32x4 a = ((const f32x4*)(yw + (size_t)(2 * t) * FN))[i];
    f32x4 b = ((const f32x4*)(yw + (size_t)(2 * t + 1) * FN))[i];
    f32x4 s = a + b;
    int base = (i >> 4) * 64 + (i & 15);
    ls[base +  0] = s.x;
    ls[base + 16] = s.y;
    ls[base + 32] = s.z;
    ls[base + 48] = s.w;
    __syncthreads();
    ((f32x4*)(out + (size_t)t * FN))[i] = ((const f32x4*)ls)[i];
}

extern "C" void kernel_launch(void* const* d_in, const int* in_sizes, int n_in,
                              void* d_out, int out_size, void* d_ws, size_t ws_size,
                              hipStream_t stream)
{
    const float* x   = (const float*)d_in[0];
    const float* We  = (const float*)d_in[1];
    const float* beb = (const float*)d_in[2];
    const float* Wg  = (const float*)d_in[3];
    const float* bg  = (const float*)d_in[4];
    float* out = (float*)d_out;

    char* ws = (char*)d_ws;
    unsigned short* xb = (unsigned short*)ws;                        // 16 MB
    unsigned short* Wb = (unsigned short*)(ws + (size_t)(16 << 20)); // 16 MB
    size_t off = (size_t)(32 << 20);
    int*   seg      = (int*)(ws + off);   off += 256;
    int*   blockcnt = (int*)(ws + off);   off += HB * NE * 4;
    int*   basebuf  = (int*)(ws + off);   off += HB * NE * 4;
    int*   meta_e   = (int*)(ws + off);   off += (size_t)NTOK * 2 * 4;
    float* meta_w   = (float*)(ws + off); off += (size_t)NTOK * 2 * 4;
    int*   ridxb    = (int*)(ws + off);   off += (size_t)NTOK * 2 * 4;
    float* rwb      = (float*)(ws + off); off += (size_t)NTOK * 2 * 4;
    void*  yw       = (void*)(ws + ((off + 255) & ~(size_t)255));
    size_t yw_base  = (size_t)((off + 255) & ~(size_t)255);

    // pick epilogue mode from available scratch (host-side, deterministic).
    int mode;
    if (ws_size >= yw_base + (size_t)NTOK * 2 * FN * 2) mode = 1;       // bf16 yw (32 MB)
    else if (ws_size >= yw_base + (size_t)NTOK * 2 * FN * 4) mode = 2;  // f32 yw (64 MB)
    else mode = 0;                                                      // atomic fallback

    k_gate<<<NTOK / 4, 256, 0, stream>>>(x, Wg, bg, xb, meta_e, meta_w);
    k_convw<<<(NE * FN * DK / 4) / 256, 256, 0, stream>>>(We, Wb);
    k_hist<<<HB, 256, 0, stream>>>(meta_e, blockcnt);
    k_scan<<<1, 64, 0, stream>>>(blockcnt, seg, basebuf);
    k_scatter<<<HB, 256, 0, stream>>>(meta_e, meta_w, basebuf, ridxb, rwb);

    const int nblk = NE * (FN / BN) * 8;   // 8 experts x 4 n-tiles x 8 m-tiles = 256
    if (mode == 1) {
        k_gemm<1><<<nblk, 512, 0, stream>>>(xb, Wb, beb, seg, ridxb, rwb, out, yw);
        k_combine_bf<<<NTOK, 256, 0, stream>>>((const unsigned short*)yw, out);
    } else if (mode == 2) {
        k_gemm<2><<<nblk, 512, 0, stream>>>(xb, Wb, beb, seg, ridxb, rwb, out, yw);
        k_combine_f32<<<NTOK, 256, 0, stream>>>((const float*)yw, out);
    } else {
        hipMemsetAsync(d_out, 0, (size_t)NTOK * FN * 4, stream);
        k_gemm<0><<<nblk, 512, 0, stream>>>(xb, Wb, beb, seg, ridxb, rwb, out, yw);
    }
}

// Round 12
// 80.600 us; speedup vs baseline: 1.0948x; 1.0617x over previous
//
#include <hip/hip_runtime.h>
#include <hip/hip_bf16.h>
#include <stdint.h>

#define NE 8
#define DK 1024
#define FN 1024
#define NTOK 8192

#define BN 256
#define BK 64
#define NIT (DK / BK)
#define H 144            // fixed per-wave rows (2 waves of M, 288-row block)

#define HB 32
#define EPB (NTOK * 2 / HB)

// LDS map per buffer: A [320 rows x 128B] @0 (40960B; rows 288..319 = clamp
// padding), B-kh0 @40960 (16384B), B-kh1 @57344 (16384B); stride 73728B x2.
#define BUFS 73728
#define BOFF 40960

#define GATE_BLOCKS (NTOK / 4)                       // 2048
#define CONV_BLOCKS (NE * FN * DK / 4 / 256)         // 8192

typedef __attribute__((ext_vector_type(4))) float f32x4;
typedef __attribute__((ext_vector_type(8))) short short8;
typedef __attribute__((ext_vector_type(4))) short short4v;

__device__ __forceinline__ unsigned short f2bf(float f) {
    union { float f; unsigned u; } v; v.f = f;
    unsigned r = v.u;
    unsigned lsb = (r >> 16) & 1u;
    r += 0x7fffu + lsb;
    return (unsigned short)(r >> 16);
}
__device__ __forceinline__ float bf2f(unsigned short u) {
    union { unsigned u; float f; } v; v.u = ((unsigned)u) << 16;
    return v.f;
}

// ---------------- fused: gating + x->bf16  |  W->bf16  (one launch) ----------
// Blocks [0, 2048): gate (one wave per token). Blocks [2048, 10240): convw.
__global__ __launch_bounds__(256) void k_prep(const float* __restrict__ x,
    const float* __restrict__ Wg, const float* __restrict__ bg,
    const float* __restrict__ W,
    unsigned short* __restrict__ xb, unsigned short* __restrict__ Wb,
    int* __restrict__ meta_e, float* __restrict__ meta_w)
{
    if (blockIdx.x >= GATE_BLOCKS) {
        // ---- convw part ----
        int i = (blockIdx.x - GATE_BLOCKS) * 256 + threadIdx.x;
        f32x4 v = ((const f32x4*)W)[i];
        short4v b;
        b.x = (short)f2bf(v.x); b.y = (short)f2bf(v.y);
        b.z = (short)f2bf(v.z); b.w = (short)f2bf(v.w);
        ((short4v*)Wb)[i] = b;
        return;
    }

    // ---- gate part ----
    const int lane = threadIdx.x & 63;
    const int t = blockIdx.x * 4 + (threadIdx.x >> 6);

    const f32x4* xr = (const f32x4*)(x + (size_t)t * DK);
    f32x4 xv[4];
#pragma unroll
    for (int c = 0; c < 4; ++c) xv[c] = xr[lane + 64 * c];

    short4v* xbo = (short4v*)(xb + (size_t)t * DK);
#pragma unroll
    for (int c = 0; c < 4; ++c) {
        short4v b;
        b.x = (short)f2bf(xv[c].x); b.y = (short)f2bf(xv[c].y);
        b.z = (short)f2bf(xv[c].z); b.w = (short)f2bf(xv[c].w);
        xbo[lane + 64 * c] = b;
    }

    float acc[NE];
#pragma unroll
    for (int e = 0; e < NE; ++e) {
        const f32x4* wr = (const f32x4*)(Wg + e * DK);
        float a = 0.f;
#pragma unroll
        for (int c = 0; c < 4; ++c) {
            f32x4 wv = wr[lane + 64 * c];
            a += xv[c].x * wv.x + xv[c].y * wv.y + xv[c].z * wv.z + xv[c].w * wv.w;
        }
        acc[e] = a;
    }
#pragma unroll
    for (int e = 0; e < NE; ++e) {
        float a = acc[e];
#pragma unroll
        for (int off = 32; off > 0; off >>= 1) a += __shfl_xor(a, off, 64);
        acc[e] = a;
    }
    if (lane == 0) {
        float v[NE];
#pragma unroll
        for (int e = 0; e < NE; ++e) v[e] = acc[e] + bg[e];
        int b0 = 0; float m0 = v[0];
#pragma unroll
        for (int e = 1; e < NE; ++e) if (v[e] > m0) { m0 = v[e]; b0 = e; }
        int b1 = -1; float m1 = -3.4e38f;
#pragma unroll
        for (int e = 0; e < NE; ++e) if (e != b0 && v[e] > m1) { m1 = v[e]; b1 = e; }
        float r = expf(m1 - m0);
        float s = 1.f + r;
        meta_e[2 * t] = b0; meta_e[2 * t + 1] = b1;
        meta_w[2 * t] = 1.f / s; meta_w[2 * t + 1] = r / s;
    }
}

// ---------------- per-block histogram (LDS atomics only) ---------------------
__global__ __launch_bounds__(256) void k_hist(const int* __restrict__ meta_e,
                                              int* __restrict__ blockcnt)
{
    __shared__ int lh[NE];
    if (threadIdx.x < NE) lh[threadIdx.x] = 0;
    __syncthreads();
    int base = blockIdx.x * EPB;
#pragma unroll
    for (int k = 0; k < EPB / 256; ++k)
        atomicAdd(&lh[meta_e[base + k * 256 + threadIdx.x]], 1);
    __syncthreads();
    if (threadIdx.x < NE) blockcnt[blockIdx.x * NE + threadIdx.x] = lh[threadIdx.x];
}

// ---------------- scatter with inline scan (k_scan folded in) ----------------
// Every block redundantly scans blockcnt (32x8 ints, L2-hot); block 0 also
// writes seg[] for k_gemm. ridx[p] = 2t+k (orig slot), rw[p] = weight.
__global__ __launch_bounds__(256) void k_scatter(const int* __restrict__ meta_e,
    const float* __restrict__ meta_w, const int* __restrict__ blockcnt,
    int* __restrict__ seg, int* __restrict__ ridx, float* __restrict__ rw)
{
    __shared__ int lh[NE];
    __shared__ int bb[NE];
    __shared__ int colsum[NE];
    __shared__ int segstart[NE];
    int tid = threadIdx.x;
    if (tid < NE) {
        lh[tid] = 0;
        int run = 0, mypre = 0;
        for (int b = 0; b < HB; ++b) {
            if (b == (int)blockIdx.x) mypre = run;
            run += blockcnt[b * NE + tid];
        }
        colsum[tid] = run;
        bb[tid] = mypre;            // prefix within column, base added below
    }
    __syncthreads();
    if (tid == 0) {
        int s = 0;
        for (int e = 0; e < NE; ++e) { segstart[e] = s; s += colsum[e]; }
        if (blockIdx.x == 0) {
            int s2 = 0;
            for (int e = 0; e < NE; ++e) { seg[e] = s2; s2 += colsum[e]; }
            seg[NE] = s2;
        }
    }
    __syncthreads();
    if (tid < NE) bb[tid] += segstart[tid];
    __syncthreads();
    int bs = blockIdx.x * EPB;
#pragma unroll
    for (int k = 0; k < EPB / 256; ++k) {
        int i = bs + k * 256 + tid;
        int e = meta_e[i];
        int r = atomicAdd(&lh[e], 1);
        int p = bb[e] + r;
        ridx[p] = i;
        rw[p] = meta_w[i];
    }
}

// ---------------- grouped GEMM: balanced 8-tiles/expert, 4-phase pipeline ----
// (byte-identical to R11 champion)
template <int MODE>
__global__ __launch_bounds__(512, 2) void k_gemm(const unsigned short* __restrict__ xb,
    const unsigned short* __restrict__ Wb, const float* __restrict__ be,
    const int* __restrict__ seg, const int* __restrict__ ridx,
    const float* __restrict__ rw, float* __restrict__ out, void* __restrict__ ywv)
{
    __shared__ char Lds[2 * BUFS];   // 144 KB

    const int bid = blockIdx.x;
    const int e = bid & 7;                       // XCD-pinned expert
    const int n0 = ((bid >> 3) & 3) * BN;
    const int mt = bid >> 5;                     // 0..7
    const int s0 = seg[e];
    const int L = seg[e + 1] - s0;
    const int lpt = (L + 7) >> 3;                // rows per m-tile
    int m0 = mt * lpt;
    const int m_end = (m0 + lpt < L) ? (m0 + lpt) : L;
    if (m0 >= m_end) return;

    const int tid = threadIdx.x;
    const int lane = tid & 63;
    const int wid = tid >> 6;
    const int wm = wid >> 2, wn = wid & 3;       // 2 x 4 wave grid
    const int frow = lane & 15;
    const int fq = lane >> 4;

    const int bgr = ((tid & 3) ^ ((tid >> 3) & 3)) * 8;
    unsigned boff[2];
#pragma unroll
    for (int c = 0; c < 2; ++c)
        boff[c] = (((unsigned)(e * FN + n0 + c * 128 + (tid >> 2))) << 10) + bgr;

    int b_base[2];
    {
        int r = wn * 64 + frow;
        int sl = fq ^ ((frow >> 1) & 3);
#pragma unroll
        for (int kk = 0; kk < 2; ++kk)
            b_base[kk] = BOFF + kk * 16384 + r * 64 + sl * 16;
    }
    int a_base[2];
#pragma unroll
    for (int kk = 0; kk < 2; ++kk)
        a_base[kk] = (wm * H + frow) * 128 + (((kk * 4 + fq) ^ (frow & 7)) * 16);

    char* LB = (char*)Lds;
    const int ag = ((tid & 7) ^ ((tid >> 3) & 7)) * 8;

    for (; m0 < m_end; m0 += 288) {
        unsigned aoff[5];
#pragma unroll
        for (int c = 0; c < 5; ++c) {
            int r = c * 64 + (tid >> 3);
            int idx = m0 + r; if (idx >= m_end) idx = m_end - 1;
            aoff[c] = (((unsigned)(ridx[s0 + idx] >> 1)) << 10) + ag;
        }

        f32x4 acc[9][4];
#pragma unroll
        for (int i = 0; i < 9; ++i)
#pragma unroll
            for (int j = 0; j < 4; ++j) acc[i][j] = f32x4{0.f, 0.f, 0.f, 0.f};

        auto STAGE_A = [&](int buf, int kt) {
            const unsigned ko = kt * BK;
            char* dst = LB + buf * BUFS + wid * 1024;
#pragma unroll
            for (int c = 0; c < 5; ++c)
                __builtin_amdgcn_global_load_lds(
                    (const __attribute__((address_space(1))) void*)(xb + aoff[c] + ko),
                    (__attribute__((address_space(3))) void*)(dst + c * 8192), 16, 0, 0);
        };
        auto STAGE_B = [&](int buf, int kt, int kh) {
            const unsigned ko = kt * BK + kh * 32;
            char* dst = LB + buf * BUFS + BOFF + kh * 16384 + wid * 1024;
#pragma unroll
            for (int c = 0; c < 2; ++c)
                __builtin_amdgcn_global_load_lds(
                    (const __attribute__((address_space(1))) void*)(Wb + boff[c] + ko),
                    (__attribute__((address_space(3))) void*)(dst + c * 8192), 16, 0, 0);
        };

#define GATE(N) do { asm volatile("s_waitcnt vmcnt(" #N ")" ::: "memory"); \
                     __builtin_amdgcn_s_barrier(); \
                     __builtin_amdgcn_sched_barrier(0); } while (0)
#define BARP  do { __builtin_amdgcn_s_barrier(); \
                   __builtin_amdgcn_sched_barrier(0); } while (0)
#define LGKM0 do { asm volatile("s_waitcnt lgkmcnt(0)" ::: "memory"); \
                   __builtin_amdgcn_sched_barrier(0); } while (0)
#define MFMA45(AF, BF, MLO, CNT) do { \
    __builtin_amdgcn_s_setprio(1); \
    _Pragma("unroll") \
    for (int mi = 0; mi < (CNT); ++mi) { \
        _Pragma("unroll") \
        for (int ni = 0; ni < 4; ++ni) \
            acc[(MLO) + mi][ni] = __builtin_amdgcn_mfma_f32_16x16x32_bf16( \
                AF[mi], BF[ni], acc[(MLO) + mi][ni], 0, 0, 0); \
    } \
    __builtin_amdgcn_s_setprio(0); } while (0)

        STAGE_A(0, 0); STAGE_B(0, 0, 0); STAGE_B(0, 0, 1);
        __builtin_amdgcn_sched_barrier(0);

        // vmcnt proof (in-order retire); per tile issue = [A:5@P0][B0:2@P1][B1:2@P2]
        // P0(t) GATE(2): outstanding A(t)5+B0(t)2+B1(t)2=9 -> retires A+B0.
        // P2(t) GATE(7): outstanding B1(t)2+A(t+1)5+B0(t+1)2=9 -> retires B1(t).
        // Last tile: GATE(0) at P2. WAR: every wave lgkm0s its reads before the
        // next barrier, so post-barrier stages never overwrite in-flight reads.
        for (int t = 0; t < NIT; ++t) {
            const int b = t & 1;
            const char* Cb = LB + b * BUFS;
            const bool st = (t + 1 < NIT);
            short8 bf[4], af[5];

            GATE(2);
#pragma unroll
            for (int ni = 0; ni < 4; ++ni)
                bf[ni] = *(const short8*)(Cb + b_base[0] + ni * 1024);
#pragma unroll
            for (int mi = 0; mi < 5; ++mi)
                af[mi] = *(const short8*)(Cb + a_base[0] + mi * 2048);
            if (st) STAGE_A(b ^ 1, t + 1);
            LGKM0;
            MFMA45(af, bf, 0, 5);

            BARP;
#pragma unroll
            for (int mi = 0; mi < 4; ++mi)
                af[mi] = *(const short8*)(Cb + a_base[0] + (5 + mi) * 2048);
            if (st) STAGE_B(b ^ 1, t + 1, 0);
            LGKM0;
            MFMA45(af, bf, 5, 4);

            if (st) { GATE(7); } else { GATE(0); }
#pragma unroll
            for (int ni = 0; ni < 4; ++ni)
                bf[ni] = *(const short8*)(Cb + b_base[1] + ni * 1024);
#pragma unroll
            for (int mi = 0; mi < 5; ++mi)
                af[mi] = *(const short8*)(Cb + a_base[1] + mi * 2048);
            if (st) STAGE_B(b ^ 1, t + 1, 1);
            LGKM0;
            MFMA45(af, bf, 0, 5);

            BARP;
#pragma unroll
            for (int mi = 0; mi < 4; ++mi)
                af[mi] = *(const short8*)(Cb + a_base[1] + (5 + mi) * 2048);
            LGKM0;
            MFMA45(af, bf, 5, 4);
        }
#undef GATE
#undef BARP
#undef LGKM0
#undef MFMA45

        float bias_n[4];
#pragma unroll
        for (int ni = 0; ni < 4; ++ni)
            bias_n[ni] = be[e * FN + n0 + wn * 64 + ni * 16 + frow];

        const int fq4 = fq * 4;
#pragma unroll
        for (int mi = 0; mi < 9; ++mi) {
#pragma unroll
            for (int j = 0; j < 4; ++j) {
                int lr = mi * 16 + fq4 + j;
                int idx = m0 + wm * H + lr;
                if (idx < m_end) {
                    float w = rw[s0 + idx];
                    int oi = ridx[s0 + idx];
                    if (MODE == 0) {
                        float* orow = out + (size_t)(oi >> 1) * FN + n0 + wn * 64 + frow;
#pragma unroll
                        for (int ni = 0; ni < 4; ++ni)
                            atomicAdd(orow + ni * 16, w * (acc[mi][ni][j] + bias_n[ni]));
                    } else if (MODE == 1) {
                        short4v pk;
                        pk.x = (short)f2bf(w * (acc[mi][0][j] + bias_n[0]));
                        pk.y = (short)f2bf(w * (acc[mi][1][j] + bias_n[1]));
                        pk.z = (short)f2bf(w * (acc[mi][2][j] + bias_n[2]));
                        pk.w = (short)f2bf(w * (acc[mi][3][j] + bias_n[3]));
                        *(short4v*)((unsigned short*)ywv + (size_t)oi * FN + n0 + wn * 64 + frow * 4) = pk;
                    } else {
                        f32x4 pk;
                        pk.x = w * (acc[mi][0][j] + bias_n[0]);
                        pk.y = w * (acc[mi][1][j] + bias_n[1]);
                        pk.z = w * (acc[mi][2][j] + bias_n[2]);
                        pk.w = w * (acc[mi][3][j] + bias_n[3]);
                        *(f32x4*)((float*)ywv + (size_t)oi * FN + n0 + wn * 64 + frow * 4) = pk;
                    }
                }
            }
        }
    }
}

// ---------------- combine: out[t] = unperm(yw[2t] + yw[2t+1]) ----------------
__global__ __launch_bounds__(256) void k_combine_bf(const unsigned short* __restrict__ yw,
                                                    float* __restrict__ out)
{
    __shared__ float ls[FN];
    int t = blockIdx.x, i = threadIdx.x;
    const unsigned* r0 = (const unsigned*)(yw + (size_t)(2 * t) * FN);
    const unsigned* r1 = (const unsigned*)(yw + (size_t)(2 * t + 1) * FN);
    unsigned a0 = r0[2 * i], a1 = r0[2 * i + 1];
    unsigned c0 = r1[2 * i], c1 = r1[2 * i + 1];
    float s0 = bf2f((unsigned short)(a0 & 0xffff)) + bf2f((unsigned short)(c0 & 0xffff));
    float s1 = bf2f((unsigned short)(a0 >> 16))    + bf2f((unsigned short)(c0 >> 16));
    float s2 = bf2f((unsigned short)(a1 & 0xffff)) + bf2f((unsigned short)(c1 & 0xffff));
    float s3 = bf2f((unsigned short)(a1 >> 16))    + bf2f((unsigned short)(c1 >> 16));
    int base = (i >> 4) * 64 + (i & 15);           // wn*64 + frow
    ls[base +  0] = s0;
    ls[base + 16] = s1;
    ls[base + 32] = s2;
    ls[base + 48] = s3;
    __syncthreads();
    ((f32x4*)(out + (size_t)t * FN))[i] = ((const f32x4*)ls)[i];
}

__global__ __launch_bounds__(256) void k_combine_f32(const float* __restrict__ yw,
                                                     float* __restrict__ out)
{
    __shared__ float ls[FN];
    int t = blockIdx.x, i = threadIdx.x;
    f32x4 a = ((const f32x4*)(yw + (size_t)(2 * t) * FN))[i];
    f32x4 b = ((const f32x4*)(yw + (size_t)(2 * t + 1) * FN))[i];
    f32x4 s = a + b;
    int base = (i >> 4) * 64 + (i & 15);
    ls[base +  0] = s.x;
    ls[base + 16] = s.y;
    ls[base + 32] = s.z;
    ls[base + 48] = s.w;
    __syncthreads();
    ((f32x4*)(out + (size_t)t * FN))[i] = ((const f32x4*)ls)[i];
}

extern "C" void kernel_launch(void* const* d_in, const int* in_sizes, int n_in,
                              void* d_out, int out_size, void* d_ws, size_t ws_size,
                              hipStream_t stream)
{
    const float* x   = (const float*)d_in[0];
    const float* We  = (const float*)d_in[1];
    const float* beb = (const float*)d_in[2];
    const float* Wg  = (const float*)d_in[3];
    const float* bg  = (const float*)d_in[4];
    float* out = (float*)d_out;

    char* ws = (char*)d_ws;
    unsigned short* xb = (unsigned short*)ws;                        // 16 MB
    unsigned short* Wb = (unsigned short*)(ws + (size_t)(16 << 20)); // 16 MB
    size_t off = (size_t)(32 << 20);
    int*   seg      = (int*)(ws + off);   off += 256;
    int*   blockcnt = (int*)(ws + off);   off += HB * NE * 4;
    int*   meta_e   = (int*)(ws + off);   off += (size_t)NTOK * 2 * 4;
    float* meta_w   = (float*)(ws + off); off += (size_t)NTOK * 2 * 4;
    int*   ridxb    = (int*)(ws + off);   off += (size_t)NTOK * 2 * 4;
    float* rwb      = (float*)(ws + off); off += (size_t)NTOK * 2 * 4;
    void*  yw       = (void*)(ws + ((off + 255) & ~(size_t)255));
    size_t yw_base  = (size_t)((off + 255) & ~(size_t)255);

    // pick epilogue mode from available scratch (host-side, deterministic).
    int mode;
    if (ws_size >= yw_base + (size_t)NTOK * 2 * FN * 2) mode = 1;       // bf16 yw (32 MB)
    else if (ws_size >= yw_base + (size_t)NTOK * 2 * FN * 4) mode = 2;  // f32 yw (64 MB)
    else mode = 0;                                                      // atomic fallback

    k_prep<<<GATE_BLOCKS + CONV_BLOCKS, 256, 0, stream>>>(x, Wg, bg, We, xb, Wb,
                                                          meta_e, meta_w);
    k_hist<<<HB, 256, 0, stream>>>(meta_e, blockcnt);
    k_scatter<<<HB, 256, 0, stream>>>(meta_e, meta_w, blockcnt, seg, ridxb, rwb);

    const int nblk = NE * (FN / BN) * 8;   // 8 experts x 4 n-tiles x 8 m-tiles = 256
    if (mode == 1) {
        k_gemm<1><<<nblk, 512, 0, stream>>>(xb, Wb, beb, seg, ridxb, rwb, out, yw);
        k_combine_bf<<<NTOK, 256, 0, stream>>>((const unsigned short*)yw, out);
    } else if (mode == 2) {
        k_gemm<2><<<nblk, 512, 0, stream>>>(xb, Wb, beb, seg, ridxb, rwb, out, yw);
        k_combine_f32<<<NTOK, 256, 0, stream>>>((const float*)yw, out);
    } else {
        hipMemsetAsync(d_out, 0, (size_t)NTOK * FN * 4, stream);
        k_gemm<0><<<nblk, 512, 0, stream>>>(xb, Wb, beb, seg, ridxb, rwb, out, yw);
    }
}